// Round 4
// baseline (99.230 us; speedup 1.0000x reference)
//
#include <hip/hip_runtime.h>
#include <hip/hip_bf16.h>

// LePEAttention (CSWin idx=0): B=16, H=W=56, DIM=256, HEADS=8, SPLIT=7
// Round 3: 2-deep software-pipelined k-loop (QK[kt+1] MFMA overlaps exp/pack[kt]),
// Q loads hoisted above staging, split-half exp->pack->PV, tree lsum, setprio
// around MFMA clusters. Structure otherwise as R2 (512 thr, permlane32_swap,
// peeled tail, conflict-free LePE restage).

#define NB    16
#define IMGH  56
#define IMGW  56
#define LTOK  3136
#define DIMC  256
#define NHEAD 8
#define HD    32
#define WS    7
#define WIN   392
#define QS    0.17677669529663687f
#define LOG2E 1.4426950408889634f

#define KROWS  416
#define KPITCH 40       // shorts per K row (80 B, 5 x 16B chunks, odd -> conflict-free b128)
#define VPITCH 424      // shorts per Vt row (848 B, 53 chunks, odd -> conflict-free)
#define NKT    13
#define NQT    13

typedef __attribute__((ext_vector_type(8)))  short short8;
typedef __attribute__((ext_vector_type(16))) float f32x16;

union U4S8 { unsigned u[4]; short8 v; };

__device__ inline short f2bf(float x) {
    __hip_bfloat16 h = __float2bfloat16(x);
    union { __hip_bfloat16 b; short s; } u; u.b = h; return u.s;
}
__device__ inline float bf2f(short s) {
    union { float f; unsigned u; } u;
    u.u = ((unsigned)(unsigned short)s) << 16; return u.f;
}
__device__ inline unsigned pk2(float a, float b) {
    return (unsigned)(unsigned short)f2bf(a) | ((unsigned)(unsigned short)f2bf(b) << 16);
}

__device__ inline float exp2v(float x) {
    float r; asm("v_exp_f32 %0, %1" : "=v"(r) : "v"(x)); return r;
}

// (a,b) -> a = {a.lo32, b.lo32}, b = {a.hi32, b.hi32} across lane<32/lane>=32.
// s_nop 1 guards the VALU-write -> V_PERMLANE*-src wait-state hazard.
__device__ inline void plswap(unsigned &a, unsigned &b) {
    asm("s_nop 1\n\tv_permlane32_swap_b32 %0, %1" : "+v"(a), "+v"(b));
}
__device__ inline void plswapf(float &a, float &b) {
    asm("s_nop 1\n\tv_permlane32_swap_b32 %0, %1" : "+v"(a), "+v"(b));
}

__global__ __launch_bounds__(512, 4) void lepe_mfma_kernel(
    const float* __restrict__ qkv,   // [3][B][L][DIM]
    const float* __restrict__ w9,    // [DIM][9]
    const float* __restrict__ bias,  // [DIM]
    float* __restrict__ out)         // [B][L][DIM]
{
    const int tid  = threadIdx.x;
    const int lane = tid & 63;
    const int wave = tid >> 6;       // 0..7
    const int blk  = blockIdx.x;
    const int hh   = blk & 7;
    const int wi   = blk >> 3;
    const int b    = wi >> 3;
    const int wb   = wi & 7;

    __shared__ __align__(16) short Kb[KROWS * KPITCH];   // 33280 B (reused as Vs)
    __shared__ __align__(16) short Vt[HD * VPITCH];      // 27136 B
    __shared__ float Ws9[HD][9];
    __shared__ float Bs[HD];
    __shared__ float InvAll[KROWS];

    const int cq = lane & 31;
    const int hi = lane >> 5;

    // ---- issue Q loads for both q-tiles BEFORE staging (latency hides under it) ----
    const int qtA = wave;
    const int qtB = wave + 8;
    const float qs = QS * LOG2E;

    auto qaddr = [&](int qt) -> const float* {
        int qtok = qt * 32 + cq; if (qtok > WIN - 1) qtok = WIN - 1;
        const int qh = qtok / WS, qw = qtok - qh * WS;
        const int ql = qh * IMGW + wb * WS + qw;
        return qkv + ((size_t)b * LTOK + ql) * DIMC + hh * HD;
    };
    const float* qpA = qaddr(qtA);
    const float* qpB = qaddr(qtB < NQT ? qtB : NQT - 1);
    const float4 Aa = *(const float4*)(qpA + hi * 8);
    const float4 Ab = *(const float4*)(qpA + hi * 8 + 4);
    const float4 Ac = *(const float4*)(qpA + 16 + hi * 8);
    const float4 Ad = *(const float4*)(qpA + 16 + hi * 8 + 4);
    const float4 Ba = *(const float4*)(qpB + hi * 8);
    const float4 Bb = *(const float4*)(qpB + hi * 8 + 4);
    const float4 Bc = *(const float4*)(qpB + 16 + hi * 8);
    const float4 Bd = *(const float4*)(qpB + 16 + hi * 8 + 4);

    // ---- stage K (row-major bf16) and V^T (d-major bf16) ----
    {
        const int sub = tid & 7;
        const int rb  = tid >> 3;        // 0..63
        for (int it = 0; it < 7; ++it) {
            const int r = it * 64 + rb;
            if (r < WIN) {
                const int h = r / WS, w = r - h * WS;
                const int l = h * IMGW + wb * WS + w;
                const size_t kb = ((size_t)(NB + b) * LTOK + l) * DIMC + hh * HD + sub * 4;
                const float4 kq = *(const float4*)(qkv + kb);
                const float4 vq = *(const float4*)(qkv + kb + (size_t)NB * LTOK * DIMC);
                short4 ks;
                ks.x = f2bf(kq.x); ks.y = f2bf(kq.y); ks.z = f2bf(kq.z); ks.w = f2bf(kq.w);
                *(short4*)&Kb[r * KPITCH + sub * 4] = ks;
                const int d0 = sub * 4;
                Vt[(d0 + 0) * VPITCH + r] = f2bf(vq.x);
                Vt[(d0 + 1) * VPITCH + r] = f2bf(vq.y);
                Vt[(d0 + 2) * VPITCH + r] = f2bf(vq.z);
                Vt[(d0 + 3) * VPITCH + r] = f2bf(vq.w);
            } else if (r < KROWS) {
                *(short4*)&Kb[r * KPITCH + sub * 4] = make_short4(0, 0, 0, 0);
            }
        }
        for (int i = tid; i < HD * (VPITCH - WIN); i += 512) {
            const int d = i >> 5;
            const int c = WIN + (i & 31);
            Vt[d * VPITCH + c] = 0;
        }
        for (int i = tid; i < HD * 9; i += 512)
            Ws9[i / 9][i % 9] = w9[(hh * HD + i / 9) * 9 + (i % 9)];
        if (tid < HD) Bs[tid] = bias[hh * HD + tid];
    }

    // ---- convert Q to bf16 B-fragments (raw float4 regs die here) ----
    U4S8 qA0, qA1, qB0, qB1;
    qA0.u[0] = pk2(Aa.x * qs, Aa.y * qs); qA0.u[1] = pk2(Aa.z * qs, Aa.w * qs);
    qA0.u[2] = pk2(Ab.x * qs, Ab.y * qs); qA0.u[3] = pk2(Ab.z * qs, Ab.w * qs);
    qA1.u[0] = pk2(Ac.x * qs, Ac.y * qs); qA1.u[1] = pk2(Ac.z * qs, Ac.w * qs);
    qA1.u[2] = pk2(Ad.x * qs, Ad.y * qs); qA1.u[3] = pk2(Ad.z * qs, Ad.w * qs);
    qB0.u[0] = pk2(Ba.x * qs, Ba.y * qs); qB0.u[1] = pk2(Ba.z * qs, Ba.w * qs);
    qB0.u[2] = pk2(Bb.x * qs, Bb.y * qs); qB0.u[3] = pk2(Bb.z * qs, Bb.w * qs);
    qB1.u[0] = pk2(Bc.x * qs, Bc.y * qs); qB1.u[1] = pk2(Bc.z * qs, Bc.w * qs);
    qB1.u[2] = pk2(Bd.x * qs, Bd.y * qs); qB1.u[3] = pk2(Bd.z * qs, Bd.w * qs);

    __syncthreads();

    f32x16 accA, accB;

    auto attn = [&](int qt, const U4S8 &qf0, const U4S8 &qf1, f32x16 &acc) {
        #pragma unroll
        for (int i = 0; i < 16; ++i) acc[i] = 0.f;
        float lsum = 0.f;

        // prologue: kt = 0
        short8 vb0c, vb1c;
        f32x16 Scur;
        {
            const short* kr = &Kb[(0 * 32 + cq) * KPITCH];
            const short8 ka0 = *(const short8*)(kr + hi * 8);
            const short8 ka1 = *(const short8*)(kr + 16 + hi * 8);
            const short* vr = &Vt[cq * VPITCH + 0 * 32 + hi * 8];
            vb0c = *(const short8*)vr;
            vb1c = *(const short8*)(vr + 16);
            #pragma unroll
            for (int i = 0; i < 16; ++i) Scur[i] = 0.f;
            __builtin_amdgcn_s_setprio(1);
            Scur = __builtin_amdgcn_mfma_f32_32x32x16_bf16(ka0, qf0.v, Scur, 0, 0, 0);
            Scur = __builtin_amdgcn_mfma_f32_32x32x16_bf16(ka1, qf1.v, Scur, 0, 0, 0);
            __builtin_amdgcn_s_setprio(0);
        }

        #pragma unroll 2
        for (int kt = 0; kt < NKT - 1; ++kt) {
            // ---- prefetch + QK for kt+1 (overlaps exp/pack of kt) ----
            const short* kr = &Kb[((kt + 1) * 32 + cq) * KPITCH];
            const short8 ka0 = *(const short8*)(kr + hi * 8);
            const short8 ka1 = *(const short8*)(kr + 16 + hi * 8);
            const short* vr = &Vt[cq * VPITCH + (kt + 1) * 32 + hi * 8];
            const short8 vb0n = *(const short8*)vr;
            const short8 vb1n = *(const short8*)(vr + 16);
            f32x16 Sn;
            #pragma unroll
            for (int i = 0; i < 16; ++i) Sn[i] = 0.f;
            __builtin_amdgcn_s_setprio(1);
            Sn = __builtin_amdgcn_mfma_f32_32x32x16_bf16(ka0, qf0.v, Sn, 0, 0, 0);
            Sn = __builtin_amdgcn_mfma_f32_32x32x16_bf16(ka1, qf1.v, Sn, 0, 0, 0);
            __builtin_amdgcn_s_setprio(0);

            // ---- process kt: half 0 ----
            const float p0 = exp2v(Scur[0]), p1 = exp2v(Scur[1]);
            const float p2 = exp2v(Scur[2]), p3 = exp2v(Scur[3]);
            const float p4 = exp2v(Scur[4]), p5 = exp2v(Scur[5]);
            const float p6 = exp2v(Scur[6]), p7 = exp2v(Scur[7]);
            lsum += ((p0 + p1) + (p2 + p3)) + ((p4 + p5) + (p6 + p7));
            unsigned u0 = pk2(p0, p1), u2 = pk2(p4, p5);
            unsigned u1 = pk2(p2, p3), u3 = pk2(p6, p7);
            plswap(u0, u2);
            plswap(u1, u3);
            U4S8 pa0; pa0.u[0] = u0; pa0.u[1] = u1; pa0.u[2] = u2; pa0.u[3] = u3;
            __builtin_amdgcn_s_setprio(1);
            acc = __builtin_amdgcn_mfma_f32_32x32x16_bf16(pa0.v, vb0c, acc, 0, 0, 0);
            __builtin_amdgcn_s_setprio(0);

            // ---- process kt: half 1 ----
            const float p8 = exp2v(Scur[8]),  p9 = exp2v(Scur[9]);
            const float pa = exp2v(Scur[10]), pb = exp2v(Scur[11]);
            const float pc = exp2v(Scur[12]), pd = exp2v(Scur[13]);
            const float pe = exp2v(Scur[14]), pf = exp2v(Scur[15]);
            lsum += ((p8 + p9) + (pa + pb)) + ((pc + pd) + (pe + pf));
            unsigned t0 = pk2(p8, p9), t2 = pk2(pc, pd);
            unsigned t1 = pk2(pa, pb), t3 = pk2(pe, pf);
            plswap(t0, t2);
            plswap(t1, t3);
            U4S8 pa1; pa1.u[0] = t0; pa1.u[1] = t1; pa1.u[2] = t2; pa1.u[3] = t3;
            __builtin_amdgcn_s_setprio(1);
            acc = __builtin_amdgcn_mfma_f32_32x32x16_bf16(pa1.v, vb1c, acc, 0, 0, 0);
            __builtin_amdgcn_s_setprio(0);

            Scur = Sn; vb0c = vb0n; vb1c = vb1n;
        }

        // ---- tail (kt = 12, k-local 0..7 valid): Scur/vb0c already hold it ----
        {
            const float p0 = exp2v(Scur[0]), p1 = exp2v(Scur[1]);
            const float p2 = exp2v(Scur[2]), p3 = exp2v(Scur[3]);
            lsum += (p0 + p1) + (p2 + p3);
            unsigned u0 = pk2(p0, p1), u2 = 0u;
            unsigned u1 = pk2(p2, p3), u3 = 0u;
            plswap(u0, u2);
            plswap(u1, u3);
            U4S8 pa0; pa0.u[0] = u0; pa0.u[1] = u1; pa0.u[2] = u2; pa0.u[3] = u3;
            __builtin_amdgcn_s_setprio(1);
            acc = __builtin_amdgcn_mfma_f32_32x32x16_bf16(pa0.v, vb0c, acc, 0, 0, 0);
            __builtin_amdgcn_s_setprio(0);
        }

        float s0 = lsum, s1 = lsum;
        plswapf(s0, s1);
        const float inv = 1.0f / (s0 + s1);
        if (hi == 0) InvAll[qt * 32 + cq] = inv;
    };

    attn(qtA, qA0, qA1, accA);
    if (qtB < NQT) attn(qtB, qB0, qB1, accB);
    __syncthreads();

    // ---- restage V row-major into Kb's dead space (conflict-free LePE reads) ----
    short* Vs = Kb;                                // 392*32 shorts = 25088 B
    for (int i = tid; i < WIN * HD; i += 512) {
        const int d = i & 31, t = i >> 5;
        Vs[t * HD + d] = Vt[d * VPITCH + t];
    }
    __syncthreads();

    auto epi = [&](int qt, f32x16 &acc) {
        #pragma unroll
        for (int r = 0; r < 16; ++r) {
            const int qrow = (r & 3) + 8 * (r >> 2) + 4 * hi;
            const int ot = qt * 32 + qrow;
            if (ot < WIN) {
                const float invr = InvAll[ot];
                const int h = ot / WS, w = ot - h * WS;
                float lp = Bs[cq];
                #pragma unroll
                for (int dy = -1; dy <= 1; ++dy) {
                    const int hy = h + dy;
                    if ((unsigned)hy >= (unsigned)IMGH) continue;
                    #pragma unroll
                    for (int dx = -1; dx <= 1; ++dx) {
                        const int wx = w + dx;
                        if ((unsigned)wx >= (unsigned)WS) continue;
                        lp += bf2f(Vs[(hy * WS + wx) * HD + cq]) * Ws9[cq][(dy + 1) * 3 + (dx + 1)];
                    }
                }
                const int l = h * IMGW + wb * WS + w;
                out[((size_t)b * LTOK + l) * DIMC + hh * HD + cq] = acc[r] * invr + lp;
            }
        }
    };

    epi(qtA, accA);
    if (qtB < NQT) epi(qtB, accB);
}

extern "C" void kernel_launch(void* const* d_in, const int* in_sizes, int n_in,
                              void* d_out, int out_size, void* d_ws, size_t ws_size,
                              hipStream_t stream) {
    const float* qkv  = (const float*)d_in[0];
    const float* w9   = (const float*)d_in[1];
    const float* bias = (const float*)d_in[2];
    float* out = (float*)d_out;

    dim3 grid(NB * 8 * NHEAD);   // 1024: one block per (window, head)
    dim3 block(512);
    lepe_mfma_kernel<<<grid, block, 0, stream>>>(qkv, w9, bias, out);
}